// Round 8
// baseline (156.376 us; speedup 1.0000x reference)
//
#include <hip/hip_runtime.h>
#include <hip/hip_bf16.h>

#define BB   4
#define NN   10000
#define EE   160000
#define FIN  256
#define HH   8
#define FO   32
#define CC   256            // H*FO
#define BN   40000          // B*N
#define BE   640000         // B*E
#define NB   157            // ceil(BN/256)

#define XCVT 5000           // BN*FIN/8/256 blocks for x cvt
#define WCVT 32             // CC*FIN/8/256 blocks for W cvt
#define CNTB 625            // BE/4/256 blocks for histogram

typedef __attribute__((ext_vector_type(8))) __bf16 bf16x8;
typedef __attribute__((ext_vector_type(4))) float  f32x4;
typedef __attribute__((ext_vector_type(2))) float  f32x2;

__device__ __forceinline__ float bf2f(unsigned short u) {
    unsigned int v = ((unsigned int)u) << 16;
    return __uint_as_float(v);
}
__device__ __forceinline__ unsigned short f2bf(float f) {
    unsigned int u = __float_as_uint(f);
    u += 0x7fffu + ((u >> 16) & 1u);   // round-to-nearest-even
    return (unsigned short)(u >> 16);
}

__device__ __forceinline__ void cvt8(const float* __restrict__ src,
                                     unsigned short* __restrict__ dst, int i)
{
    const float4* s = (const float4*)src + (size_t)i * 2;
    float4 v0 = s[0], v1 = s[1];
    float f[8] = {v0.x, v0.y, v0.z, v0.w, v1.x, v1.y, v1.z, v1.w};
    union { unsigned short u[8]; uint4 q; } o;
#pragma unroll
    for (int j = 0; j < 8; ++j) o.u[j] = f2bf(f[j]);
    ((uint4*)dst)[i] = o.q;
}

// 256-thread block exclusive scan (int). lds4 is a __shared__ int[4].
__device__ __forceinline__ int block_excl_scan_256(int v, int t, int* lds4,
                                                   int* total)
{
    int lane = t & 63, wid = t >> 6;
    int incl = v;
#pragma unroll
    for (int off = 1; off < 64; off <<= 1) {
        int u = __shfl_up(incl, off);
        if (lane >= off) incl += u;
    }
    if (lane == 63) lds4[wid] = incl;
    __syncthreads();
    int w0 = lds4[0], w1 = lds4[1], w2 = lds4[2], w3 = lds4[3];
    int woff = (wid > 0 ? w0 : 0) + (wid > 1 ? w1 : 0) + (wid > 2 ? w2 : 0);
    *total = w0 + w1 + w2 + w3;
    return woff + incl - v;
}

// ---------------------------------------------------------------------------
// Kernel P: fused prep — cvt x->bf16, cvt W->bf16, deg histogram.
// ---------------------------------------------------------------------------
__global__ __launch_bounds__(256) void k_prep(
    const float* __restrict__ x, const float* __restrict__ Wm,
    const int* __restrict__ ei, unsigned short* __restrict__ xb,
    unsigned short* __restrict__ wb, int* __restrict__ deg)
{
    int blk = blockIdx.x, t = threadIdx.x;
    if (blk < XCVT) {
        cvt8(x, xb, blk * 256 + t);
    } else if (blk < XCVT + WCVT) {
        cvt8(Wm, wb, (blk - XCVT) * 256 + t);
    } else {
        int i = (blk - XCVT - WCVT) * 256 + t;      // 4 edges per thread
        int e0 = i * 4;
        int b  = e0 / EE;
        int le = e0 - b * EE;
        int4 tq = *(const int4*)(ei + (size_t)b * 2 * EE + EE + le);
        int base = b * NN;
        atomicAdd(&deg[tq.x + base], 1);
        atomicAdd(&deg[tq.y + base], 1);
        atomicAdd(&deg[tq.z + base], 1);
        atomicAdd(&deg[tq.w + base], 1);
    }
}

// ---------------------------------------------------------------------------
// Kernel 1: proj = xb @ Wb^T via MFMA bf16 (128x128 tile, BK=64, 4 waves)
// + fused per-node scores: each wave's 64-col span = 2 whole heads; dot with
// a_src/a_trg from f32 accumulators, 16-lane butterfly reduce, direct store.
// ---------------------------------------------------------------------------
__global__ __launch_bounds__(256) void k_gemm(
    const unsigned short* __restrict__ xb, const unsigned short* __restrict__ wb,
    const float* __restrict__ a_src, const float* __restrict__ a_trg,
    unsigned short* __restrict__ proj, float* __restrict__ ssrc,
    float* __restrict__ strg)
{
    __shared__ alignas(16) unsigned short As[128 * 64];
    __shared__ alignas(16) unsigned short Bs[128 * 64];

    const int t    = threadIdx.x;
    const int lane = t & 63;
    const int wid  = t >> 6;
    const int wr   = wid >> 1, wc = wid & 1;
    const int bm   = blockIdx.x >> 1;
    const int bn   = blockIdx.x & 1;
    const int row0 = bm * 128, col0 = bn * 128;

    const int srow = t >> 3;
    const int scol = (t & 7) * 8;

    f32x4 acc[4][4] = {};

    for (int kt = 0; kt < 4; ++kt) {
        const int k0 = kt * 64;
#pragma unroll
        for (int p = 0; p < 4; ++p) {
            int tr = p * 32 + srow;
            int cg = scol ^ ((tr & 7) << 3);
            int gra = row0 + tr; if (gra > BN - 1) gra = BN - 1;
            const unsigned short* ga = xb + (size_t)gra * FIN + k0 + cg;
            const unsigned short* gb = wb + (size_t)(col0 + tr) * FIN + k0 + cg;
            __builtin_amdgcn_global_load_lds(
                (const __attribute__((address_space(1))) void*)ga,
                (__attribute__((address_space(3))) void*)&As[p * 2048 + t * 8],
                16, 0, 0);
            __builtin_amdgcn_global_load_lds(
                (const __attribute__((address_space(1))) void*)gb,
                (__attribute__((address_space(3))) void*)&Bs[p * 2048 + t * 8],
                16, 0, 0);
        }
        __syncthreads();

#pragma unroll
        for (int kk = 0; kk < 2; ++kk) {
            bf16x8 af[4], bfr[4];
#pragma unroll
            for (int m = 0; m < 4; ++m) {
                int row = wr * 64 + m * 16 + (lane & 15);
                int col = (kk * 32 + (lane >> 4) * 8) ^ ((row & 7) << 3);
                af[m] = *(const bf16x8*)&As[row * 64 + col];
            }
#pragma unroll
            for (int n = 0; n < 4; ++n) {
                int row = wc * 64 + n * 16 + (lane & 15);
                int col = (kk * 32 + (lane >> 4) * 8) ^ ((row & 7) << 3);
                bfr[n] = *(const bf16x8*)&Bs[row * 64 + col];
            }
#pragma unroll
            for (int m = 0; m < 4; ++m)
#pragma unroll
                for (int n = 0; n < 4; ++n)
                    acc[m][n] = __builtin_amdgcn_mfma_f32_16x16x32_bf16(
                        af[m], bfr[n], acc[m][n], 0, 0, 0);
        }
        __syncthreads();
    }

    const int lg    = lane & 15;
    const int rbase = row0 + wr * 64 + (lane >> 4) * 4;
    const int cbase = col0 + wc * 64 + lg;

    // C write (bf16 proj)
#pragma unroll
    for (int m = 0; m < 4; ++m)
#pragma unroll
        for (int n = 0; n < 4; ++n)
#pragma unroll
            for (int j = 0; j < 4; ++j) {
                int r = rbase + m * 16 + j;
                int c = cbase + n * 16;
                if (r < BN) proj[(size_t)r * CC + c] = f2bf(acc[m][n][j]);
            }

    // fused score epilogue: heads h0 = bn*4 + wc*2 (cols n=0,1), h0+1 (n=2,3)
    float as0[4], at0[4];
#pragma unroll
    for (int n = 0; n < 4; ++n) {
        int col = cbase + n * 16;
        as0[n] = a_src[col];
        at0[n] = a_trg[col];
    }
    const int h0 = bn * 4 + wc * 2;
#pragma unroll
    for (int m = 0; m < 4; ++m)
#pragma unroll
        for (int j = 0; j < 4; ++j) {
            float vs0 = acc[m][0][j] * as0[0] + acc[m][1][j] * as0[1];
            float vs1 = acc[m][2][j] * as0[2] + acc[m][3][j] * as0[3];
            float vt0 = acc[m][0][j] * at0[0] + acc[m][1][j] * at0[1];
            float vt1 = acc[m][2][j] * at0[2] + acc[m][3][j] * at0[3];
#pragma unroll
            for (int off = 1; off < 16; off <<= 1) {     // stays in 16-group
                vs0 += __shfl_xor(vs0, off);
                vs1 += __shfl_xor(vs1, off);
                vt0 += __shfl_xor(vt0, off);
                vt1 += __shfl_xor(vt1, off);
            }
            int r = rbase + m * 16 + j;                  // uniform in 16-group
            if (r < BN) {
                if      (lg == 0) ssrc[(size_t)r * HH + h0]     = vs0;
                else if (lg == 1) ssrc[(size_t)r * HH + h0 + 1] = vs1;
                else if (lg == 2) strg[(size_t)r * HH + h0]     = vt0;
                else if (lg == 3) strg[(size_t)r * HH + h0 + 1] = vt1;
            }
        }
}

// ---------------------------------------------------------------------------
// Scan: bsum (157 blocks) -> fill (157 blocks, computes its own block offset
// by reducing bsum[t < bid]). cursor[i] = CSR start; after k_edge = CSR end.
// ---------------------------------------------------------------------------
__global__ __launch_bounds__(256) void k_bsum(
    const int* __restrict__ deg, int* __restrict__ bsum)
{
    __shared__ int w4[4];
    int t = threadIdx.x, i = blockIdx.x * 256 + t;
    int v = (i < BN) ? deg[i] : 0;
#pragma unroll
    for (int off = 32; off >= 1; off >>= 1) v += __shfl_xor(v, off);
    if ((t & 63) == 0) w4[t >> 6] = v;
    __syncthreads();
    if (t == 0) bsum[blockIdx.x] = w4[0] + w4[1] + w4[2] + w4[3];
}

__global__ __launch_bounds__(256) void k_fill(
    const int* __restrict__ deg, const int* __restrict__ bsum,
    int* __restrict__ cursor)
{
    __shared__ int w4a[4];
    __shared__ int w4b[4];
    int t = threadIdx.x, bid = blockIdx.x, i = bid * 256 + t;

    // block offset = sum of bsum[0..bid)  (t < bid <= 156 < NB)
    int bv = (t < bid) ? bsum[t] : 0;
#pragma unroll
    for (int off = 32; off >= 1; off >>= 1) bv += __shfl_xor(bv, off);
    if ((t & 63) == 0) w4a[t >> 6] = bv;
    __syncthreads();
    int boff = w4a[0] + w4a[1] + w4a[2] + w4a[3];

    int v = (i < BN) ? deg[i] : 0;
    int total;
    int excl = block_excl_scan_256(v, t, w4b, &total);
    if (i < BN) cursor[i] = boff + excl;
}

// ---------------------------------------------------------------------------
// Kernel C: 4 edges/thread, coalesced loads, 4 independent atomic chains;
// single 4B scattered store per edge (src | mask-bit).
// ---------------------------------------------------------------------------
__global__ __launch_bounds__(256) void k_edge(
    const int* __restrict__ ei, const float* __restrict__ mask,
    int* __restrict__ cursor, int* __restrict__ esrc)
{
    int i = blockIdx.x * 256 + threadIdx.x;     // [0, BE/4)
    if (i >= BE / 4) return;
    int e0 = i * 4;
    int b  = e0 / EE;                            // EE%4==0 -> uniform batch
    int le = e0 - b * EE;
    const int* eb = ei + (size_t)b * 2 * EE;
    int4   sq = *(const int4*)(eb + le);
    int4   tq = *(const int4*)(eb + EE + le);
    float4 mq = *(const float4*)(mask + e0);
    int base = b * NN;

    int p0 = atomicAdd(&cursor[tq.x + base], 1);
    int p1 = atomicAdd(&cursor[tq.y + base], 1);
    int p2 = atomicAdd(&cursor[tq.z + base], 1);
    int p3 = atomicAdd(&cursor[tq.w + base], 1);
    esrc[p0] = (sq.x + base) | (mq.x > 0.f ? 0 : (int)0x80000000);
    esrc[p1] = (sq.y + base) | (mq.y > 0.f ? 0 : (int)0x80000000);
    esrc[p2] = (sq.z + base) | (mq.z > 0.f ? 0 : (int)0x80000000);
    esrc[p3] = (sq.w + base) | (mq.w > 0.f ? 0 : (int)0x80000000);
}

// ---------------------------------------------------------------------------
// Kernel D: one wave per target node, 16 edges per outer step (two 8-edge
// groups' score chains issued together for 2x MLP). Lane l computes exp for
// (edge l&7, head l>>3); __shfl distributes. den from own-lane exps + final
// 3-step reduce. f32x2 accumulators for packed FMA.
// ---------------------------------------------------------------------------
__global__ __launch_bounds__(256) void k_gather(
    const int* __restrict__ cursor, const int* __restrict__ esrc,
    const float* __restrict__ ssrc, const float* __restrict__ strg,
    const unsigned short* __restrict__ proj, const float* __restrict__ bias,
    float* __restrict__ out)
{
    int gid  = blockIdx.x * 256 + threadIdx.x;
    int node = gid >> 6;
    int lane = gid & 63;
    if (node >= BN) return;
    int h  = lane >> 3;
    int el = lane & 7;
    int hb = lane & 56;
    float st = strg[(size_t)node * HH + h];
    int lo = node ? cursor[node - 1] : 0;
    int hi = cursor[node];

    f32x2 acc01 = {0.f, 0.f}, acc23 = {0.f, 0.f};
    float deno = 0.f;

    for (int p = lo; p < hi; p += 16) {
        int  i0 = p + el,  i1 = p + 8 + el;
        bool v0 = i0 < hi, v1 = i1 < hi;
        int sv0 = esrc[v0 ? i0 : lo];
        int sv1 = esrc[v1 ? i1 : lo];
        int s0  = sv0 & 0x7fffffff, s1 = sv1 & 0x7fffffff;
        float f0 = ssrc[(size_t)s0 * HH + h];
        float f1 = ssrc[(size_t)s1 * HH + h];
        float c0 = f0 + st; c0 = c0 > 0.f ? c0 : 0.2f * c0;
        float c1 = f1 + st; c1 = c1 > 0.f ? c1 : 0.2f * c1;
        float ex0 = (v0 && sv0 >= 0) ? __expf(c0) : 0.f;
        float ex1 = (v1 && sv1 >= 0) ? __expf(c1) : 0.f;
        deno += ex0 + ex1;                       // own-lane edges only

#pragma unroll
        for (int e = 0; e < 8; ++e) {
            float ee = __shfl(ex0, e | hb);
            int   se = __shfl(s0, e);
            ushort4 q = ((const ushort4*)(proj + (size_t)se * CC))[lane];
            f32x2 p01 = { bf2f(q.x), bf2f(q.y) };
            f32x2 p23 = { bf2f(q.z), bf2f(q.w) };
            acc01 += p01 * ee;
            acc23 += p23 * ee;
        }
        if (p + 8 < hi) {
#pragma unroll
            for (int e = 0; e < 8; ++e) {
                float ee = __shfl(ex1, e | hb);
                int   se = __shfl(s1, e);
                ushort4 q = ((const ushort4*)(proj + (size_t)se * CC))[lane];
                f32x2 p01 = { bf2f(q.x), bf2f(q.y) };
                f32x2 p23 = { bf2f(q.z), bf2f(q.w) };
                acc01 += p01 * ee;
                acc23 += p23 * ee;
            }
        }
    }

    // den = sum over the 8 lanes of this head group (xor toggles el bits)
#pragma unroll
    for (int off = 1; off < 8; off <<= 1) deno += __shfl_xor(deno, off);

    float inv = 1.f / (deno + 1e-16f);
    float4 bv = ((const float4*)bias)[lane];
    float o0 = acc01[0] * inv + bv.x, o1 = acc01[1] * inv + bv.y;
    float o2 = acc23[0] * inv + bv.z, o3 = acc23[1] * inv + bv.w;
    o0 = o0 > 0.f ? o0 : __expf(o0) - 1.f;
    o1 = o1 > 0.f ? o1 : __expf(o1) - 1.f;
    o2 = o2 > 0.f ? o2 : __expf(o2) - 1.f;
    o3 = o3 > 0.f ? o3 : __expf(o3) - 1.f;
    ((float4*)(out + (size_t)node * CC))[lane] = make_float4(o0, o1, o2, o3);
}

// ---------------------------------------------------------------------------
extern "C" void kernel_launch(void* const* d_in, const int* in_sizes, int n_in,
                              void* d_out, int out_size, void* d_ws, size_t ws_size,
                              hipStream_t stream)
{
    const float* x     = (const float*)d_in[0];
    const int*   ei    = (const int*)  d_in[1];
    const float* mask  = (const float*)d_in[2];
    const float* Wm    = (const float*)d_in[3];
    const float* a_src = (const float*)d_in[4];
    const float* a_trg = (const float*)d_in[5];
    const float* bias  = (const float*)d_in[6];
    float* out = (float*)d_out;

    char* ws = (char*)d_ws;
    size_t off = 0;
    unsigned short* xb = (unsigned short*)(ws + off); off += (size_t)BN * FIN * 2; // 20.48 MB
    unsigned short* wb = (unsigned short*)(ws + off); off += (size_t)CC * FIN * 2; //  0.13 MB
    unsigned short* proj = (unsigned short*)(ws + off); off += (size_t)BN * CC * 2;// 20.48 MB
    float* ssrc = (float*)(ws + off); off += (size_t)BN * HH * 4;                  //  1.28 MB
    float* strg = (float*)(ws + off); off += (size_t)BN * HH * 4;                  //  1.28 MB
    int*   bsum = (int*)  (ws + off); off += 256 * 4;
    int*   deg    = (int*)(ws + off); off += (size_t)BN * 4;                       //  0.16 MB
    int*   cursor = (int*)(ws + off); off += (size_t)BN * 4;                       //  0.16 MB
    int*   esrc   = (int*)(ws + off); off += (size_t)BE * 4;                       //  2.56 MB

    hipMemsetAsync(deg, 0, (size_t)BN * 4, stream);
    k_prep <<<XCVT + WCVT + CNTB, 256, 0, stream>>>(x, Wm, ei, xb, wb, deg);
    k_gemm <<<((BN + 127) / 128) * 2, 256, 0, stream>>>(xb, wb, a_src, a_trg,
                                                        proj, ssrc, strg);
    k_bsum <<<NB, 256, 0, stream>>>(deg, bsum);
    k_fill <<<NB, 256, 0, stream>>>(deg, bsum, cursor);
    k_edge <<<(BE / 4 + 255) / 256, 256, 0, stream>>>(ei, mask, cursor, esrc);
    k_gather<<<(BN * 64) / 256, 256, 0, stream>>>(cursor, esrc, ssrc, strg,
                                                  proj, bias, out);
}

// Round 9
// 141.177 us; speedup vs baseline: 1.1077x; 1.1077x over previous
//
#include <hip/hip_runtime.h>
#include <hip/hip_bf16.h>

#define BB   4
#define NN   10000
#define EE   160000
#define FIN  256
#define HH   8
#define FO   32
#define CC   256            // H*FO
#define BN   40000          // B*N
#define BE   640000         // B*E
#define NB   157            // ceil(BN/256)

#define WCVT 32             // CC*FIN/8/256 blocks for W cvt
#define CNTB 625            // BE/4/256 blocks for histogram

typedef __attribute__((ext_vector_type(8))) __bf16 bf16x8;
typedef __attribute__((ext_vector_type(4))) float  f32x4;

__device__ __forceinline__ float bf2f(unsigned short u) {
    unsigned int v = ((unsigned int)u) << 16;
    return __uint_as_float(v);
}
__device__ __forceinline__ unsigned short f2bf(float f) {
    unsigned int u = __float_as_uint(f);
    u += 0x7fffu + ((u >> 16) & 1u);   // round-to-nearest-even
    return (unsigned short)(u >> 16);
}
// pack two f32 -> two bf16 (RNE) in one instruction
__device__ __forceinline__ unsigned int cvtpk(float lo, float hi) {
    unsigned int r;
    asm volatile("v_cvt_pk_bf16_f32 %0, %1, %2" : "=v"(r) : "v"(lo), "v"(hi));
    return r;
}

__device__ __forceinline__ void cvt8(const float* __restrict__ src,
                                     unsigned short* __restrict__ dst, int i)
{
    const float4* s = (const float4*)src + (size_t)i * 2;
    float4 v0 = s[0], v1 = s[1];
    float f[8] = {v0.x, v0.y, v0.z, v0.w, v1.x, v1.y, v1.z, v1.w};
    union { unsigned short u[8]; uint4 q; } o;
#pragma unroll
    for (int j = 0; j < 8; ++j) o.u[j] = f2bf(f[j]);
    ((uint4*)dst)[i] = o.q;
}

// 256-thread block exclusive scan (int). lds4 is a __shared__ int[4].
__device__ __forceinline__ int block_excl_scan_256(int v, int t, int* lds4,
                                                   int* total)
{
    int lane = t & 63, wid = t >> 6;
    int incl = v;
#pragma unroll
    for (int off = 1; off < 64; off <<= 1) {
        int u = __shfl_up(incl, off);
        if (lane >= off) incl += u;
    }
    if (lane == 63) lds4[wid] = incl;
    __syncthreads();
    int w0 = lds4[0], w1 = lds4[1], w2 = lds4[2], w3 = lds4[3];
    int woff = (wid > 0 ? w0 : 0) + (wid > 1 ? w1 : 0) + (wid > 2 ? w2 : 0);
    *total = w0 + w1 + w2 + w3;
    return woff + incl - v;
}

// ---------------------------------------------------------------------------
// Kernel P: W->bf16 cvt (pre-swizzle not needed: wb is read via
// global_load_lds with pre-swizzled source addressing in k_gemm) + deg histo.
// ---------------------------------------------------------------------------
__global__ __launch_bounds__(256) void k_prep(
    const float* __restrict__ Wm, const int* __restrict__ ei,
    unsigned short* __restrict__ wb, int* __restrict__ deg)
{
    int blk = blockIdx.x, t = threadIdx.x;
    if (blk < WCVT) {
        cvt8(Wm, wb, blk * 256 + t);
    } else {
        int i = (blk - WCVT) * 256 + t;             // 4 edges per thread
        int e0 = i * 4;
        int b  = e0 / EE;
        int le = e0 - b * EE;
        int4 tq = *(const int4*)(ei + (size_t)b * 2 * EE + EE + le);
        int base = b * NN;
        atomicAdd(&deg[tq.x + base], 1);
        atomicAdd(&deg[tq.y + base], 1);
        atomicAdd(&deg[tq.z + base], 1);
        atomicAdd(&deg[tq.w + base], 1);
    }
}

// ---------------------------------------------------------------------------
// Kernel 1: proj = x @ Wb^T via MFMA bf16 (128x128 tile, BK=64, 4 waves).
// A staged from f32 x with on-the-fly cvt_pk->bf16 and explicit swizzled
// ds_write (both-sides swizzle); B staged via global_load_lds from
// pre-swizzled wb source addresses.
// ---------------------------------------------------------------------------
__global__ __launch_bounds__(256) void k_gemm(
    const float* __restrict__ x, const unsigned short* __restrict__ wb,
    unsigned short* __restrict__ proj)
{
    __shared__ alignas(16) unsigned short As[128 * 64];
    __shared__ alignas(16) unsigned short Bs[128 * 64];

    const int t    = threadIdx.x;
    const int lane = t & 63;
    const int wid  = t >> 6;
    const int wr   = wid >> 1, wc = wid & 1;
    const int bm   = blockIdx.x >> 1;
    const int bn   = blockIdx.x & 1;
    const int row0 = bm * 128, col0 = bn * 128;

    const int srow = t >> 3;            // 0..31
    const int scol = (t & 7) * 8;

    f32x4 acc[4][4] = {};

    for (int kt = 0; kt < 4; ++kt) {
        const int k0 = kt * 64;
#pragma unroll
        for (int p = 0; p < 4; ++p) {
            int tr = p * 32 + srow;                       // tile row 0..127
            int swz = (tr & 7) << 3;
            int gra = row0 + tr; if (gra > BN - 1) gra = BN - 1;  // M-tail
            // ---- A: f32 load + cvt + swizzled LDS write
            const float4* xa = (const float4*)(x + (size_t)gra * FIN + k0 + scol);
            float4 v0 = xa[0], v1 = xa[1];
            uint4 w;
            w.x = cvtpk(v0.x, v0.y);
            w.y = cvtpk(v0.z, v0.w);
            w.z = cvtpk(v1.x, v1.y);
            w.w = cvtpk(v1.z, v1.w);
            *(uint4*)&As[tr * 64 + (scol ^ swz)] = w;
            // ---- B: direct-to-LDS from pre-swizzled source
            const unsigned short* gb = wb + (size_t)(col0 + tr) * FIN + k0 + (scol ^ swz);
            __builtin_amdgcn_global_load_lds(
                (const __attribute__((address_space(1))) void*)gb,
                (__attribute__((address_space(3))) void*)&Bs[p * 2048 + t * 8],
                16, 0, 0);
        }
        __syncthreads();

#pragma unroll
        for (int kk = 0; kk < 2; ++kk) {
            bf16x8 af[4], bfr[4];
#pragma unroll
            for (int m = 0; m < 4; ++m) {
                int row = wr * 64 + m * 16 + (lane & 15);
                int col = (kk * 32 + (lane >> 4) * 8) ^ ((row & 7) << 3);
                af[m] = *(const bf16x8*)&As[row * 64 + col];
            }
#pragma unroll
            for (int n = 0; n < 4; ++n) {
                int row = wc * 64 + n * 16 + (lane & 15);
                int col = (kk * 32 + (lane >> 4) * 8) ^ ((row & 7) << 3);
                bfr[n] = *(const bf16x8*)&Bs[row * 64 + col];
            }
#pragma unroll
            for (int m = 0; m < 4; ++m)
#pragma unroll
                for (int n = 0; n < 4; ++n)
                    acc[m][n] = __builtin_amdgcn_mfma_f32_16x16x32_bf16(
                        af[m], bfr[n], acc[m][n], 0, 0, 0);
        }
        __syncthreads();
    }

    const int rbase = row0 + wr * 64 + (lane >> 4) * 4;
    const int cbase = col0 + wc * 64 + (lane & 15);
#pragma unroll
    for (int m = 0; m < 4; ++m)
#pragma unroll
        for (int n = 0; n < 4; ++n)
#pragma unroll
            for (int j = 0; j < 4; ++j) {
                int r = rbase + m * 16 + j;
                int c = cbase + n * 16;
                if (r < BN) proj[(size_t)r * CC + c] = f2bf(acc[m][n][j]);
            }
}

// ---------------------------------------------------------------------------
// Kernel 2: per-node attention scores (node = blk*32 + t>>3, head = t&7)
// ---------------------------------------------------------------------------
__global__ __launch_bounds__(256) void k_score(
    const unsigned short* __restrict__ proj,
    const float* __restrict__ a_src, const float* __restrict__ a_trg,
    float* __restrict__ ssrc, float* __restrict__ strg)
{
    __shared__ float sa[CC], sb[CC];
    int t = threadIdx.x;
    sa[t] = a_src[t];
    sb[t] = a_trg[t];
    __syncthreads();
    int node = blockIdx.x * 32 + (t >> 3);
    int h    = t & 7;
    const uint4* q4 = (const uint4*)(proj + (size_t)node * CC + h * 32);
    const float* pa = sa + h * 32;
    const float* pb = sb + h * 32;
    float vs = 0.f, vt = 0.f;
#pragma unroll
    for (int i = 0; i < 4; ++i) {
        uint4 q = q4[i];
        unsigned int v[4] = {q.x, q.y, q.z, q.w};
#pragma unroll
        for (int j = 0; j < 4; ++j) {
            float lo = __uint_as_float(v[j] << 16);
            float hi = __uint_as_float(v[j] & 0xffff0000u);
            int c = i * 8 + j * 2;
            vs += lo * pa[c] + hi * pa[c + 1];
            vt += lo * pb[c] + hi * pb[c + 1];
        }
    }
    ssrc[(size_t)node * HH + h] = vs;
    strg[(size_t)node * HH + h] = vt;
}

// ---------------------------------------------------------------------------
// Scan: bsum (157 blocks) -> fill (157 blocks, self-computed block offset).
// cursor[i] = CSR start; after k_edge, cursor[i] = CSR end.
// ---------------------------------------------------------------------------
__global__ __launch_bounds__(256) void k_bsum(
    const int* __restrict__ deg, int* __restrict__ bsum)
{
    __shared__ int w4[4];
    int t = threadIdx.x, i = blockIdx.x * 256 + t;
    int v = (i < BN) ? deg[i] : 0;
#pragma unroll
    for (int off = 32; off >= 1; off >>= 1) v += __shfl_xor(v, off);
    if ((t & 63) == 0) w4[t >> 6] = v;
    __syncthreads();
    if (t == 0) bsum[blockIdx.x] = w4[0] + w4[1] + w4[2] + w4[3];
}

__global__ __launch_bounds__(256) void k_fill(
    const int* __restrict__ deg, const int* __restrict__ bsum,
    int* __restrict__ cursor)
{
    __shared__ int w4a[4];
    __shared__ int w4b[4];
    int t = threadIdx.x, bid = blockIdx.x, i = bid * 256 + t;

    int bv = (t < bid) ? bsum[t] : 0;
#pragma unroll
    for (int off = 32; off >= 1; off >>= 1) bv += __shfl_xor(bv, off);
    if ((t & 63) == 0) w4a[t >> 6] = bv;
    __syncthreads();
    int boff = w4a[0] + w4a[1] + w4a[2] + w4a[3];

    int v = (i < BN) ? deg[i] : 0;
    int total;
    int excl = block_excl_scan_256(v, t, w4b, &total);
    if (i < BN) cursor[i] = boff + excl;
}

// ---------------------------------------------------------------------------
// Kernel C: 4 edges/thread, coalesced loads, 4 independent atomic chains;
// single 4B scattered store per edge (src | mask-bit).
// ---------------------------------------------------------------------------
__global__ __launch_bounds__(256) void k_edge(
    const int* __restrict__ ei, const float* __restrict__ mask,
    int* __restrict__ cursor, int* __restrict__ esrc)
{
    int i = blockIdx.x * 256 + threadIdx.x;     // [0, BE/4)
    if (i >= BE / 4) return;
    int e0 = i * 4;
    int b  = e0 / EE;                            // EE%4==0 -> uniform batch
    int le = e0 - b * EE;
    const int* eb = ei + (size_t)b * 2 * EE;
    int4   sq = *(const int4*)(eb + le);
    int4   tq = *(const int4*)(eb + EE + le);
    float4 mq = *(const float4*)(mask + e0);
    int base = b * NN;

    int p0 = atomicAdd(&cursor[tq.x + base], 1);
    int p1 = atomicAdd(&cursor[tq.y + base], 1);
    int p2 = atomicAdd(&cursor[tq.z + base], 1);
    int p3 = atomicAdd(&cursor[tq.w + base], 1);
    esrc[p0] = (sq.x + base) | (mq.x > 0.f ? 0 : (int)0x80000000);
    esrc[p1] = (sq.y + base) | (mq.y > 0.f ? 0 : (int)0x80000000);
    esrc[p2] = (sq.z + base) | (mq.z > 0.f ? 0 : (int)0x80000000);
    esrc[p3] = (sq.w + base) | (mq.w > 0.f ? 0 : (int)0x80000000);
}

// ---------------------------------------------------------------------------
// Kernel D: one wave per target node, 8 edges/step (R7 structure) + depth-2
// prefetch of the next group's esrc/ssrc chain. Lane l owns exp for
// (edge l&7, head l>>3); __shfl distributes. Own-lane den + 3-shuffle reduce.
// ---------------------------------------------------------------------------
__global__ __launch_bounds__(256) void k_gather(
    const int* __restrict__ cursor, const int* __restrict__ esrc,
    const float* __restrict__ ssrc, const float* __restrict__ strg,
    const unsigned short* __restrict__ proj, const float* __restrict__ bias,
    float* __restrict__ out)
{
    int gid  = blockIdx.x * 256 + threadIdx.x;
    int node = gid >> 6;
    int lane = gid & 63;
    if (node >= BN) return;
    int h  = lane >> 3;
    int el = lane & 7;
    int hb = lane & 56;
    float st = strg[(size_t)node * HH + h];
    int lo = node ? cursor[node - 1] : 0;
    int hi = cursor[node];

    float acc0 = 0.f, acc1 = 0.f, acc2 = 0.f, acc3 = 0.f, deno = 0.f;

    // prologue: load group 0's chain
    int  i0 = lo + el;
    bool v0 = i0 < hi;
    int  sv = v0 ? esrc[i0] : 0;
    int  s  = sv & 0x7fffffff;
    float f = ssrc[(size_t)s * HH + h];

    for (int p = lo; p < hi; p += 8) {
        // prefetch next group's chain (consumed next iteration; hidden
        // under this iteration's 8 proj-gathers)
        int  i1 = p + 8 + el;
        bool v1 = i1 < hi;
        int  svn = v1 ? esrc[i1] : 0;
        float fn = ssrc[(size_t)(svn & 0x7fffffff) * HH + h];

        float c = f + st;
        c = c > 0.f ? c : 0.2f * c;                // leaky_relu(0.2)
        float ex = (v0 && sv >= 0) ? __expf(c) : 0.f;
        deno += ex;                                 // own-lane edge only

#pragma unroll
        for (int e = 0; e < 8; ++e) {
            float ee = __shfl(ex, e | hb);          // (edge e, this head)
            int   se = __shfl(s, e);
            ushort4 q = ((const ushort4*)(proj + (size_t)se * CC))[lane];
            acc0 += bf2f(q.x) * ee;
            acc1 += bf2f(q.y) * ee;
            acc2 += bf2f(q.z) * ee;
            acc3 += bf2f(q.w) * ee;
        }
        sv = svn; s = svn & 0x7fffffff; f = fn; v0 = v1;
    }

    // den: sum over the 8 el-lanes of this head group
#pragma unroll
    for (int off = 1; off < 8; off <<= 1) deno += __shfl_xor(deno, off);

    float inv = 1.f / (deno + 1e-16f);
    float4 bv = ((const float4*)bias)[lane];
    float o0 = acc0 * inv + bv.x, o1 = acc1 * inv + bv.y;
    float o2 = acc2 * inv + bv.z, o3 = acc3 * inv + bv.w;
    o0 = o0 > 0.f ? o0 : __expf(o0) - 1.f;
    o1 = o1 > 0.f ? o1 : __expf(o1) - 1.f;
    o2 = o2 > 0.f ? o2 : __expf(o2) - 1.f;
    o3 = o3 > 0.f ? o3 : __expf(o3) - 1.f;
    ((float4*)(out + (size_t)node * CC))[lane] = make_float4(o0, o1, o2, o3);
}

// ---------------------------------------------------------------------------
extern "C" void kernel_launch(void* const* d_in, const int* in_sizes, int n_in,
                              void* d_out, int out_size, void* d_ws, size_t ws_size,
                              hipStream_t stream)
{
    const float* x     = (const float*)d_in[0];
    const int*   ei    = (const int*)  d_in[1];
    const float* mask  = (const float*)d_in[2];
    const float* Wm    = (const float*)d_in[3];
    const float* a_src = (const float*)d_in[4];
    const float* a_trg = (const float*)d_in[5];
    const float* bias  = (const float*)d_in[6];
    float* out = (float*)d_out;

    char* ws = (char*)d_ws;
    size_t off = 0;
    unsigned short* wb = (unsigned short*)(ws + off); off += (size_t)CC * FIN * 2; //  0.13 MB
    unsigned short* proj = (unsigned short*)(ws + off); off += (size_t)BN * CC * 2;// 20.48 MB
    float* ssrc = (float*)(ws + off); off += (size_t)BN * HH * 4;                  //  1.28 MB
    float* strg = (float*)(ws + off); off += (size_t)BN * HH * 4;                  //  1.28 MB
    int*   bsum = (int*)  (ws + off); off += 256 * 4;
    int*   deg    = (int*)(ws + off); off += (size_t)BN * 4;                       //  0.16 MB
    int*   cursor = (int*)(ws + off); off += (size_t)BN * 4;                       //  0.16 MB
    int*   esrc   = (int*)(ws + off); off += (size_t)(BE + 64) * 4;                //  2.56 MB

    hipMemsetAsync(deg, 0, (size_t)BN * 4, stream);
    k_prep <<<WCVT + CNTB, 256, 0, stream>>>(Wm, ei, wb, deg);
    k_gemm <<<((BN + 127) / 128) * 2, 256, 0, stream>>>(x, wb, proj);
    k_score<<<BN / 32, 256, 0, stream>>>(proj, a_src, a_trg, ssrc, strg);
    k_bsum <<<NB, 256, 0, stream>>>(deg, bsum);
    k_fill <<<NB, 256, 0, stream>>>(deg, bsum, cursor);
    k_edge <<<(BE / 4 + 255) / 256, 256, 0, stream>>>(ei, mask, cursor, esrc);
    k_gather<<<(BN * 64) / 256, 256, 0, stream>>>(cursor, esrc, ssrc, strg,
                                                  proj, bias, out);
}